// Round 4
// baseline (204.766 us; speedup 1.0000x reference)
//
#include <hip/hip_runtime.h>
#include <math.h>

#define BS 16
#define N 512
#define NF 7
#define HID 64

typedef float nfloat4 __attribute__((ext_vector_type(4)));

// ---------------------------------------------------------------------------
// Fused prep kernel.
//   blocks 0..15  : per-batch masked mean removal -> xcpad (float4, w=0)
//   blocks 16..47 : he = silu(h@W1+b1)@W2+b2, one thread per node -> he
// ---------------------------------------------------------------------------
__global__ __launch_bounds__(256) void prep_kernel(const float* __restrict__ x,
                                                   const float* __restrict__ mask,
                                                   const float* __restrict__ h,
                                                   const float* __restrict__ W1,
                                                   const float* __restrict__ b1,
                                                   const float* __restrict__ W2,
                                                   const float* __restrict__ b2,
                                                   float4* __restrict__ xcpad,
                                                   float2* __restrict__ he) {
    const int t = threadIdx.x;

    if (blockIdx.x < BS) {
        // ---- centering for batch b ----
        const int b = blockIdx.x;
        float lx[2], ly[2], lz[2], lm[2];
        float sx = 0.f, sy = 0.f, sz = 0.f, sm = 0.f;
        for (int k = 0; k < 2; ++k) {
            const int j = t + k * 256;
            const float* p = x + ((size_t)b * N + j) * 3;
            const float m = mask[(size_t)b * N + j];
            lx[k] = p[0]; ly[k] = p[1]; lz[k] = p[2]; lm[k] = m;
            sx += lx[k] * m; sy += ly[k] * m; sz += lz[k] * m; sm += m;
        }
        for (int off = 32; off > 0; off >>= 1) {
            sx += __shfl_down(sx, off, 64);
            sy += __shfl_down(sy, off, 64);
            sz += __shfl_down(sz, off, 64);
            sm += __shfl_down(sm, off, 64);
        }
        __shared__ float red[4][4];
        __shared__ float meanv[3];
        const int wave = t >> 6, lane = t & 63;
        if (lane == 0) { red[wave][0] = sx; red[wave][1] = sy; red[wave][2] = sz; red[wave][3] = sm; }
        __syncthreads();
        if (t == 0) {
            float tx = 0.f, ty = 0.f, tz = 0.f, tm = 0.f;
            for (int w = 0; w < 4; ++w) { tx += red[w][0]; ty += red[w][1]; tz += red[w][2]; tm += red[w][3]; }
            meanv[0] = tx / tm; meanv[1] = ty / tm; meanv[2] = tz / tm;
        }
        __syncthreads();
        const float mx = meanv[0], my = meanv[1], mz = meanv[2];
        for (int k = 0; k < 2; ++k) {
            const int j = t + k * 256;
            const float m = lm[k];
            xcpad[(size_t)b * N + j] =
                make_float4((lx[k] - mx) * m, (ly[k] - my) * m, (lz[k] - mz) * m, 0.f);
        }
    } else {
        // ---- MLP for node chunk ----
        __shared__ float sW1[NF * HID];
        __shared__ float sb1[HID];
        __shared__ float sW2[HID * 2];
        for (int idx = t; idx < NF * HID; idx += 256) sW1[idx] = W1[idx];
        if (t < HID) sb1[t] = b1[t];
        if (t < HID * 2) sW2[t] = W2[t];
        __syncthreads();

        const int node = (blockIdx.x - BS) * 256 + t;
        float hv[NF];
        for (int j = 0; j < NF; ++j) hv[j] = h[(size_t)node * NF + j];
        float o0 = b2[0], o1 = b2[1];
        for (int k = 0; k < HID; ++k) {
            float a = sb1[k];
            for (int j = 0; j < NF; ++j) a += hv[j] * sW1[j * HID + k];
            const float s = a / (1.f + __expf(-a));   // silu (fast exp; abs err ~1e-5)
            o0 += s * sW2[k * 2 + 0];
            o1 += s * sW2[k * 2 + 1];
        }
        he[node] = make_float2(o0, o1);
    }
}

// ---------------------------------------------------------------------------
// Edge kernel. Block = one (b,i) row; 256 threads, 2 j's per thread.
// One xj/hj load + one radial/tc computation per j, two nt float4 stores.
// (Store pattern proven perf-neutral vs lane-contiguous in R0 vs R3 A/B;
//  this variant halves the loads + VALU.)
// nt: 128 MiB stream with no reuse — keep it from thrashing L2's row set.
// ---------------------------------------------------------------------------
__global__ __launch_bounds__(256) void edge_kernel(const float4* __restrict__ xcpad,
                                                   const float2* __restrict__ he,
                                                   const float* __restrict__ pose,
                                                   nfloat4* __restrict__ out) {
    const int i = blockIdx.x;
    const int b = blockIdx.y;
    const int t = threadIdx.x;
    const int node_i = b * N + i;

    const float4 xi = xcpad[node_i];
    const float2 hi = he[node_i];
    const float* pp = pose + (size_t)node_i * 9;
    const float p00 = pp[0], p01 = pp[1], p02 = pp[2];
    const float p10 = pp[3], p11 = pp[4], p12 = pp[5];
    const float p20 = pp[6], p21 = pp[7], p22 = pp[8];

    nfloat4* __restrict__ orow = out + (size_t)node_i * N * 2;

    #pragma unroll
    for (int k = 0; k < 2; ++k) {
        const int j = t + k * 256;
        const float4 xj = xcpad[b * N + j];
        const float2 hj = he[b * N + j];
        const float c0 = xi.x - xj.x, c1 = xi.y - xj.y, c2 = xi.z - xj.z;
        const float r = c0 * c0 + c1 * c1 + c2 * c2;
        const float inv = 1.0f / (sqrtf(r + 1e-8f) + 1.0f);
        const float d0 = c0 * inv, d1 = c1 * inv, d2 = c2 * inv;
        const float t0 = p00 * d0 + p01 * d1 + p02 * d2;
        const float t1 = p10 * d0 + p11 * d1 + p12 * d2;
        const float t2 = p20 * d0 + p21 * d1 + p22 * d2;
        nfloat4 v0, v1;
        v0.x = r;    v0.y = t0;   v0.z = t1;   v0.w = t2;
        v1.x = hi.x; v1.y = hi.y; v1.z = hj.x; v1.w = hj.y;
        __builtin_nontemporal_store(v0, orow + j * 2);
        __builtin_nontemporal_store(v1, orow + j * 2 + 1);
    }
}

extern "C" void kernel_launch(void* const* d_in, const int* in_sizes, int n_in,
                              void* d_out, int out_size, void* d_ws, size_t ws_size,
                              hipStream_t stream) {
    const float* x    = (const float*)d_in[0];  // [16, 512, 3]
    const float* h    = (const float*)d_in[1];  // [8192, 7]
    const float* pose = (const float*)d_in[2];  // [8192, 3, 3]
    const float* mask = (const float*)d_in[3];  // [16, 512, 1]
    const float* W1   = (const float*)d_in[4];  // [7, 64]
    const float* b1   = (const float*)d_in[5];  // [64]
    const float* W2   = (const float*)d_in[6];  // [64, 2]
    const float* b2   = (const float*)d_in[7];  // [2]
    nfloat4* out = (nfloat4*)d_out;

    float4* xcpad = (float4*)d_ws;                                   // 8192 * 16 B
    float2* hebuf = (float2*)((char*)d_ws + (size_t)BS * N * 16);    // 8192 *  8 B

    hipLaunchKernelGGL(prep_kernel, dim3(BS + BS * N / 256), dim3(256), 0, stream,
                       x, mask, h, W1, b1, W2, b2, xcpad, hebuf);
    hipLaunchKernelGGL(edge_kernel, dim3(N, BS), dim3(256), 0, stream,
                       xcpad, hebuf, pose, out);
}

// Round 5
// 158.474 us; speedup vs baseline: 1.2921x; 1.2921x over previous
//
#include <hip/hip_runtime.h>
#include <math.h>

#define BS 16
#define N 512
#define NF 7
#define HID 64

// ---------------------------------------------------------------------------
// Fused prep kernel.
//   blocks 0..15  : per-batch masked mean removal -> xcpad (float4, w=0)
//   blocks 16..47 : he = silu(h@W1+b1)@W2+b2, one thread per node -> he
// ---------------------------------------------------------------------------
__global__ __launch_bounds__(256) void prep_kernel(const float* __restrict__ x,
                                                   const float* __restrict__ mask,
                                                   const float* __restrict__ h,
                                                   const float* __restrict__ W1,
                                                   const float* __restrict__ b1,
                                                   const float* __restrict__ W2,
                                                   const float* __restrict__ b2,
                                                   float4* __restrict__ xcpad,
                                                   float2* __restrict__ he) {
    const int t = threadIdx.x;

    if (blockIdx.x < BS) {
        // ---- centering for batch b ----
        const int b = blockIdx.x;
        float lx[2], ly[2], lz[2], lm[2];
        float sx = 0.f, sy = 0.f, sz = 0.f, sm = 0.f;
        for (int k = 0; k < 2; ++k) {
            const int j = t + k * 256;
            const float* p = x + ((size_t)b * N + j) * 3;
            const float m = mask[(size_t)b * N + j];
            lx[k] = p[0]; ly[k] = p[1]; lz[k] = p[2]; lm[k] = m;
            sx += lx[k] * m; sy += ly[k] * m; sz += lz[k] * m; sm += m;
        }
        for (int off = 32; off > 0; off >>= 1) {
            sx += __shfl_down(sx, off, 64);
            sy += __shfl_down(sy, off, 64);
            sz += __shfl_down(sz, off, 64);
            sm += __shfl_down(sm, off, 64);
        }
        __shared__ float red[4][4];
        __shared__ float meanv[3];
        const int wave = t >> 6, lane = t & 63;
        if (lane == 0) { red[wave][0] = sx; red[wave][1] = sy; red[wave][2] = sz; red[wave][3] = sm; }
        __syncthreads();
        if (t == 0) {
            float tx = 0.f, ty = 0.f, tz = 0.f, tm = 0.f;
            for (int w = 0; w < 4; ++w) { tx += red[w][0]; ty += red[w][1]; tz += red[w][2]; tm += red[w][3]; }
            meanv[0] = tx / tm; meanv[1] = ty / tm; meanv[2] = tz / tm;
        }
        __syncthreads();
        const float mx = meanv[0], my = meanv[1], mz = meanv[2];
        for (int k = 0; k < 2; ++k) {
            const int j = t + k * 256;
            const float m = lm[k];
            xcpad[(size_t)b * N + j] =
                make_float4((lx[k] - mx) * m, (ly[k] - my) * m, (lz[k] - mz) * m, 0.f);
        }
    } else {
        // ---- MLP for node chunk ----
        __shared__ float sW1[NF * HID];
        __shared__ float sb1[HID];
        __shared__ float sW2[HID * 2];
        for (int idx = t; idx < NF * HID; idx += 256) sW1[idx] = W1[idx];
        if (t < HID) sb1[t] = b1[t];
        if (t < HID * 2) sW2[t] = W2[t];
        __syncthreads();

        const int node = (blockIdx.x - BS) * 256 + t;
        float hv[NF];
        for (int j = 0; j < NF; ++j) hv[j] = h[(size_t)node * NF + j];
        float o0 = b2[0], o1 = b2[1];
        for (int k = 0; k < HID; ++k) {
            float a = sb1[k];
            for (int j = 0; j < NF; ++j) a += hv[j] * sW1[j * HID + k];
            const float s = a / (1.f + __expf(-a));   // silu (fast exp; abs err ~1e-5)
            o0 += s * sW2[k * 2 + 0];
            o1 += s * sW2[k * 2 + 1];
        }
        he[node] = make_float2(o0, o1);
    }
}

// ---------------------------------------------------------------------------
// Edge kernel. Block = one (b,i) row. Row = 512 j * 8 floats = 1024 float4.
// Lane-contiguous stores: idx = k*256+t selects float4 #idx of the row;
// j = idx>>1, half = idx&1. Every wave store = one contiguous aligned 1 KiB
// segment. REGULAR stores (L2 write-back merges; nt+strided was the R4
// regression, nt+contig was neutral — fills hit 6.4 TB/s with regular stores).
// Even/odd lanes duplicate the radial/tc math; VALU is ~2% busy, free.
// ---------------------------------------------------------------------------
__global__ __launch_bounds__(256) void edge_kernel(const float4* __restrict__ xcpad,
                                                   const float2* __restrict__ he,
                                                   const float* __restrict__ pose,
                                                   float4* __restrict__ out) {
    const int i = blockIdx.x;
    const int b = blockIdx.y;
    const int t = threadIdx.x;
    const int node_i = b * N + i;

    const float4 xi = xcpad[node_i];
    const float2 hi = he[node_i];
    const float* pp = pose + (size_t)node_i * 9;
    const float p00 = pp[0], p01 = pp[1], p02 = pp[2];
    const float p10 = pp[3], p11 = pp[4], p12 = pp[5];
    const float p20 = pp[6], p21 = pp[7], p22 = pp[8];

    float4* __restrict__ orow = out + (size_t)node_i * N * 2;

    #pragma unroll
    for (int k = 0; k < 4; ++k) {
        const int idx = k * 256 + t;
        const int j = idx >> 1;
        const float4 xj = xcpad[b * N + j];
        const float2 hj = he[b * N + j];
        const float c0 = xi.x - xj.x, c1 = xi.y - xj.y, c2 = xi.z - xj.z;
        const float r = c0 * c0 + c1 * c1 + c2 * c2;
        const float inv = 1.0f / (sqrtf(r + 1e-8f) + 1.0f);
        const float d0 = c0 * inv, d1 = c1 * inv, d2 = c2 * inv;
        const float t0 = p00 * d0 + p01 * d1 + p02 * d2;
        const float t1 = p10 * d0 + p11 * d1 + p12 * d2;
        const float t2 = p20 * d0 + p21 * d1 + p22 * d2;
        const float4 v = (idx & 1) ? make_float4(hi.x, hi.y, hj.x, hj.y)
                                   : make_float4(r, t0, t1, t2);
        orow[idx] = v;
    }
}

extern "C" void kernel_launch(void* const* d_in, const int* in_sizes, int n_in,
                              void* d_out, int out_size, void* d_ws, size_t ws_size,
                              hipStream_t stream) {
    const float* x    = (const float*)d_in[0];  // [16, 512, 3]
    const float* h    = (const float*)d_in[1];  // [8192, 7]
    const float* pose = (const float*)d_in[2];  // [8192, 3, 3]
    const float* mask = (const float*)d_in[3];  // [16, 512, 1]
    const float* W1   = (const float*)d_in[4];  // [7, 64]
    const float* b1   = (const float*)d_in[5];  // [64]
    const float* W2   = (const float*)d_in[6];  // [64, 2]
    const float* b2   = (const float*)d_in[7];  // [2]
    float4* out = (float4*)d_out;

    float4* xcpad = (float4*)d_ws;                                   // 8192 * 16 B
    float2* hebuf = (float2*)((char*)d_ws + (size_t)BS * N * 16);    // 8192 *  8 B

    hipLaunchKernelGGL(prep_kernel, dim3(BS + BS * N / 256), dim3(256), 0, stream,
                       x, mask, h, W1, b1, W2, b2, xcpad, hebuf);
    hipLaunchKernelGGL(edge_kernel, dim3(N, BS), dim3(256), 0, stream,
                       xcpad, hebuf, pose, out);
}